// Round 1
// baseline (1884.855 us; speedup 1.0000x reference)
//
#include <hip/hip_runtime.h>

// VGAE GCN encoder: mu, sigma = GCN heads over shared GCN layer.
// n=100000, f=256, hid=128, dout=64, E=1.6M (values read from in_sizes).

#define HID 128
#define DOUT 64

// ---- degree: deg[dst]++ over edges (self-loop +1 folded into dis_kernel) ----
__global__ void deg_kernel(const int* __restrict__ dst, float* __restrict__ deg, int E) {
    int e = blockIdx.x * blockDim.x + threadIdx.x;
    if (e < E) atomicAdd(&deg[dst[e]], 1.0f);
}

// deg -> dis = rsqrt(deg + 1) in place
__global__ void dis_kernel(float* __restrict__ deg, int n) {
    int i = blockIdx.x * blockDim.x + threadIdx.x;
    if (i < n) deg[i] = rsqrtf(deg[i] + 1.0f);
}

// ---- tiled fp32 GEMM: C[M,128] = A[M,K] @ B[K,128].  BM=32, BK=64, 256 thr ----
template <int K>
__global__ __launch_bounds__(256) void gemm_kernel(const float* __restrict__ A,
                                                   const float* __restrict__ B,
                                                   float* __restrict__ C, int M) {
    __shared__ float As[32][68];    // +4 pad breaks power-of-2 row stride
    __shared__ float Bs[64][128];
    const int block_row = blockIdx.x * 32;
    const int tid = threadIdx.x;
    const int tx = tid & 31;   // col group: cols tx*4..tx*4+3
    const int ty = tid >> 5;   // row group: rows ty*4..ty*4+3

    float acc[4][4] = {};

    for (int k0 = 0; k0 < K; k0 += 64) {
        // A tile: 32 rows x 64 cols = 512 float4
        for (int l = tid; l < 32 * 16; l += 256) {
            int r = l >> 4, c4 = l & 15;
            float4 v = ((const float4*)(A + (size_t)(block_row + r) * K + k0))[c4];
            As[r][c4 * 4 + 0] = v.x; As[r][c4 * 4 + 1] = v.y;
            As[r][c4 * 4 + 2] = v.z; As[r][c4 * 4 + 3] = v.w;
        }
        // B tile: 64 rows x 128 cols = 2048 float4
        for (int l = tid; l < 64 * 32; l += 256) {
            int r = l >> 5, c4 = l & 31;
            ((float4*)&Bs[r][0])[c4] = ((const float4*)(B + (size_t)(k0 + r) * HID))[c4];
        }
        __syncthreads();

        #pragma unroll
        for (int kk = 0; kk < 64; kk++) {
            float a[4], b[4];
            #pragma unroll
            for (int i = 0; i < 4; i++) a[i] = As[ty * 4 + i][kk];
            #pragma unroll
            for (int j = 0; j < 4; j++) b[j] = Bs[kk][tx * 4 + j];
            #pragma unroll
            for (int i = 0; i < 4; i++)
                #pragma unroll
                for (int j = 0; j < 4; j++) acc[i][j] += a[i] * b[j];
        }
        __syncthreads();
    }

    #pragma unroll
    for (int i = 0; i < 4; i++) {
        int r = block_row + ty * 4 + i;
        if (r < M) {
            float4 v = make_float4(acc[i][0], acc[i][1], acc[i][2], acc[i][3]);
            *((float4*)(C + (size_t)r * HID + tx * 4)) = v;
        }
    }
}

// ---- Wcat[k][0:64]=Wmu[k], Wcat[k][64:128]=Wvar[k] ----
__global__ void wcat_kernel(const float* __restrict__ Wmu, const float* __restrict__ Wvar,
                            float* __restrict__ Wcat) {
    int i = blockIdx.x * blockDim.x + threadIdx.x;   // 128*128
    int k = i >> 7, j = i & 127;
    Wcat[i] = (j < DOUT) ? Wmu[k * DOUT + j] : Wvar[k * DOUT + (j - DOUT)];
}

// ---- scatter layer 1: agg[dst] += h[src] * dis[src]*dis[dst], 128 thr/edge ----
__global__ __launch_bounds__(256) void scatter1_kernel(const int* __restrict__ src,
                                                       const int* __restrict__ dst,
                                                       const float* __restrict__ dis,
                                                       const float* __restrict__ h,
                                                       float* __restrict__ agg, int E) {
    int e = blockIdx.x * 2 + (threadIdx.x >> 7);
    if (e >= E) return;
    int j = threadIdx.x & 127;
    int s = src[e], d = dst[e];
    float norm = dis[s] * dis[d];
    atomicAdd(&agg[(size_t)d * HID + j], h[(size_t)s * HID + j] * norm);
}

// ---- h1 = relu(agg + selfloop(h*dis^2) + b1), in place in agg ----
__global__ void relu_kernel(float* __restrict__ agg, const float* __restrict__ h,
                            const float* __restrict__ dis, const float* __restrict__ b1,
                            int total) {
    int i = blockIdx.x * blockDim.x + threadIdx.x;   // n*128
    if (i >= total) return;
    int node = i >> 7, j = i & 127;
    float d = dis[node];
    float v = agg[i] + h[i] * d * d + b1[j];
    agg[i] = v > 0.f ? v : 0.f;
}

// ---- scatter layer 2: mu/sigma halves of the fused 128-wide projection ----
__global__ __launch_bounds__(256) void scatter2_kernel(const int* __restrict__ src,
                                                       const int* __restrict__ dst,
                                                       const float* __restrict__ dis,
                                                       const float* __restrict__ hms,
                                                       float* __restrict__ out_mu,
                                                       float* __restrict__ out_sig, int E) {
    int e = blockIdx.x * 2 + (threadIdx.x >> 7);
    if (e >= E) return;
    int j = threadIdx.x & 127;
    int s = src[e], d = dst[e];
    float norm = dis[s] * dis[d];
    float v = hms[(size_t)s * HID + j] * norm;
    if (j < DOUT) atomicAdd(&out_mu[(size_t)d * DOUT + j], v);
    else          atomicAdd(&out_sig[(size_t)d * DOUT + (j - DOUT)], v);
}

// ---- final: add self-loop contribution + biases ----
__global__ void outbias_kernel(float* __restrict__ out_mu, float* __restrict__ out_sig,
                               const float* __restrict__ hms, const float* __restrict__ dis,
                               const float* __restrict__ bmu, const float* __restrict__ bvar,
                               int total) {
    int i = blockIdx.x * blockDim.x + threadIdx.x;   // n*64
    if (i >= total) return;
    int node = i / DOUT, j = i % DOUT;
    float d2 = dis[node]; d2 *= d2;
    out_mu[i]  += hms[(size_t)node * HID + j] * d2 + bmu[j];
    out_sig[i] += hms[(size_t)node * HID + DOUT + j] * d2 + bvar[j];
}

extern "C" void kernel_launch(void* const* d_in, const int* in_sizes, int n_in,
                              void* d_out, int out_size, void* d_ws, size_t ws_size,
                              hipStream_t stream) {
    const float* x    = (const float*)d_in[0];
    const int*   ei   = (const int*)d_in[1];
    const float* W1   = (const float*)d_in[2];
    const float* b1   = (const float*)d_in[3];
    const float* Wmu  = (const float*)d_in[4];
    const float* bmu  = (const float*)d_in[5];
    const float* Wvar = (const float*)d_in[6];
    const float* bvar = (const float*)d_in[7];

    const int n = in_sizes[0] / 256;     // 100000
    const int E = in_sizes[1] / 2;       // 1600000
    const int* src = ei;
    const int* dst = ei + E;

    // workspace layout
    char* ws = (char*)d_ws;
    size_t off = 0;
    float* deg = (float*)(ws + off); off += ((size_t)n * 4 + 255) & ~(size_t)255;
    float* Wcat = (float*)(ws + off); off += (size_t)HID * HID * 4;
    off = (off + 255) & ~(size_t)255;
    float* h   = (float*)(ws + off); off += (size_t)n * HID * 4;   // also reused for hms
    float* agg = (float*)(ws + off); off += (size_t)n * HID * 4;   // also h1 in place

    float* out_mu  = (float*)d_out;
    float* out_sig = (float*)d_out + (size_t)n * DOUT;

    hipMemsetAsync(deg, 0, (size_t)n * 4, stream);
    hipMemsetAsync(agg, 0, (size_t)n * HID * 4, stream);
    hipMemsetAsync(d_out, 0, (size_t)out_size * 4, stream);

    deg_kernel<<<(E + 255) / 256, 256, 0, stream>>>(dst, deg, E);
    dis_kernel<<<(n + 255) / 256, 256, 0, stream>>>(deg, n);

    gemm_kernel<256><<<(n + 31) / 32, 256, 0, stream>>>(x, W1, h, n);
    scatter1_kernel<<<(E + 1) / 2, 256, 0, stream>>>(src, dst, deg, h, agg, E);
    relu_kernel<<<((n * HID) + 255) / 256, 256, 0, stream>>>(agg, h, deg, b1, n * HID);

    wcat_kernel<<<(HID * HID) / 256, 256, 0, stream>>>(Wmu, Wvar, Wcat);
    gemm_kernel<128><<<(n + 31) / 32, 256, 0, stream>>>(agg, Wcat, h, n);
    scatter2_kernel<<<(E + 1) / 2, 256, 0, stream>>>(src, dst, deg, h, out_mu, out_sig, E);
    outbias_kernel<<<((n * DOUT) + 255) / 256, 256, 0, stream>>>(out_mu, out_sig, h, deg,
                                                                 bmu, bvar, n * DOUT);
}

// Round 2
// 784.045 us; speedup vs baseline: 2.4040x; 2.4040x over previous
//
#include <hip/hip_runtime.h>

// VGAE GCN encoder, CSR-based (no feature-wide atomics).
// n=100000, f=256, hid=128, dout=64, E=1.6M (read from in_sizes).

#define HID 128
#define DOUT 64

// ---- degree histogram over dst ----
__global__ void deg_kernel(const int* __restrict__ dst, int* __restrict__ deg, int E) {
    int e = blockIdx.x * blockDim.x + threadIdx.x;
    if (e < E) atomicAdd(&deg[dst[e]], 1);
}

// dis = rsqrt(deg + 1)   (self-loop folded into +1)
__global__ void dis_kernel(const int* __restrict__ deg, float* __restrict__ dis, int n) {
    int i = blockIdx.x * blockDim.x + threadIdx.x;
    if (i < n) dis[i] = rsqrtf((float)deg[i] + 1.0f);
}

// ---- 3-kernel exclusive scan of deg -> rowptr (1024 elems/block) ----
__global__ __launch_bounds__(256) void scan1_kernel(const int* __restrict__ deg,
                                                    int* __restrict__ rowptr,
                                                    int* __restrict__ bsum, int n) {
    __shared__ int s[256];
    int b = blockIdx.x, t = threadIdx.x;
    int base = b * 1024 + t * 4;
    int v0 = 0, v1 = 0, v2 = 0, v3 = 0;
    if (base + 0 < n) v0 = deg[base + 0];
    if (base + 1 < n) v1 = deg[base + 1];
    if (base + 2 < n) v2 = deg[base + 2];
    if (base + 3 < n) v3 = deg[base + 3];
    int tsum = v0 + v1 + v2 + v3;
    s[t] = tsum;
    __syncthreads();
    for (int off = 1; off < 256; off <<= 1) {
        int x = (t >= off) ? s[t - off] : 0;
        __syncthreads();
        s[t] += x;
        __syncthreads();
    }
    int excl = s[t] - tsum;
    if (base + 0 < n) rowptr[base + 0] = excl;
    if (base + 1 < n) rowptr[base + 1] = excl + v0;
    if (base + 2 < n) rowptr[base + 2] = excl + v0 + v1;
    if (base + 3 < n) rowptr[base + 3] = excl + v0 + v1 + v2;
    if (t == 255) bsum[b] = s[255];
}

__global__ void scan2_kernel(int* __restrict__ bsum, int nb) {
    if (threadIdx.x == 0 && blockIdx.x == 0) {
        int run = 0;
        for (int i = 0; i < nb; i++) { int t = bsum[i]; bsum[i] = run; run += t; }
    }
}

__global__ void scan3_kernel(int* __restrict__ rowptr, const int* __restrict__ bsum, int n) {
    int i = blockIdx.x * blockDim.x + threadIdx.x;
    if (i < n) rowptr[i] += bsum[i >> 10];
}

// ---- CSR fill: advances rowptr to inclusive form; col[pos] = src ----
__global__ void fill_kernel(const int* __restrict__ src, const int* __restrict__ dst,
                            int* __restrict__ rowptr, int* __restrict__ col, int E) {
    int e = blockIdx.x * blockDim.x + threadIdx.x;
    if (e < E) {
        int d = dst[e];
        int pos = atomicAdd(&rowptr[d], 1);
        col[pos] = src[e];
    }
}

// ---- tiled fp32 GEMM: C[M,128] = A[M,K] @ B[K,128].  BM=32, BK=64, 256 thr ----
template <int K>
__global__ __launch_bounds__(256) void gemm_kernel(const float* __restrict__ A,
                                                   const float* __restrict__ B,
                                                   float* __restrict__ C, int M) {
    __shared__ float As[32][68];
    __shared__ float Bs[64][128];
    const int block_row = blockIdx.x * 32;
    const int tid = threadIdx.x;
    const int tx = tid & 31;
    const int ty = tid >> 5;

    float acc[4][4] = {};

    for (int k0 = 0; k0 < K; k0 += 64) {
        for (int l = tid; l < 32 * 16; l += 256) {
            int r = l >> 4, c4 = l & 15;
            float4 v = ((const float4*)(A + (size_t)(block_row + r) * K + k0))[c4];
            As[r][c4 * 4 + 0] = v.x; As[r][c4 * 4 + 1] = v.y;
            As[r][c4 * 4 + 2] = v.z; As[r][c4 * 4 + 3] = v.w;
        }
        for (int l = tid; l < 64 * 32; l += 256) {
            int r = l >> 5, c4 = l & 31;
            ((float4*)&Bs[r][0])[c4] = ((const float4*)(B + (size_t)(k0 + r) * HID))[c4];
        }
        __syncthreads();

        #pragma unroll
        for (int kk = 0; kk < 64; kk++) {
            float a[4], b[4];
            #pragma unroll
            for (int i = 0; i < 4; i++) a[i] = As[ty * 4 + i][kk];
            #pragma unroll
            for (int j = 0; j < 4; j++) b[j] = Bs[kk][tx * 4 + j];
            #pragma unroll
            for (int i = 0; i < 4; i++)
                #pragma unroll
                for (int j = 0; j < 4; j++) acc[i][j] += a[i] * b[j];
        }
        __syncthreads();
    }

    #pragma unroll
    for (int i = 0; i < 4; i++) {
        int r = block_row + ty * 4 + i;
        if (r < M) {
            float4 v = make_float4(acc[i][0], acc[i][1], acc[i][2], acc[i][3]);
            *((float4*)(C + (size_t)r * HID + tx * 4)) = v;
        }
    }
}

// ---- GEMM2 with fused bias + mu/sigma split epilogue ----
__global__ __launch_bounds__(256) void gemm2_kernel(const float* __restrict__ A,
                                                    const float* __restrict__ B,
                                                    const float* __restrict__ bmu,
                                                    const float* __restrict__ bvar,
                                                    float* __restrict__ out_mu,
                                                    float* __restrict__ out_sig, int M) {
    __shared__ float As[32][68];
    __shared__ float Bs[64][128];
    const int block_row = blockIdx.x * 32;
    const int tid = threadIdx.x;
    const int tx = tid & 31;
    const int ty = tid >> 5;

    float acc[4][4] = {};

    for (int k0 = 0; k0 < HID; k0 += 64) {
        for (int l = tid; l < 32 * 16; l += 256) {
            int r = l >> 4, c4 = l & 15;
            float4 v = ((const float4*)(A + (size_t)(block_row + r) * HID + k0))[c4];
            As[r][c4 * 4 + 0] = v.x; As[r][c4 * 4 + 1] = v.y;
            As[r][c4 * 4 + 2] = v.z; As[r][c4 * 4 + 3] = v.w;
        }
        for (int l = tid; l < 64 * 32; l += 256) {
            int r = l >> 5, c4 = l & 31;
            ((float4*)&Bs[r][0])[c4] = ((const float4*)(B + (size_t)(k0 + r) * HID))[c4];
        }
        __syncthreads();

        #pragma unroll
        for (int kk = 0; kk < 64; kk++) {
            float a[4], b[4];
            #pragma unroll
            for (int i = 0; i < 4; i++) a[i] = As[ty * 4 + i][kk];
            #pragma unroll
            for (int j = 0; j < 4; j++) b[j] = Bs[kk][tx * 4 + j];
            #pragma unroll
            for (int i = 0; i < 4; i++)
                #pragma unroll
                for (int j = 0; j < 4; j++) acc[i][j] += a[i] * b[j];
        }
        __syncthreads();
    }

    const int j0 = tx * 4;
    float4 bias = (j0 < DOUT) ? *((const float4*)(bmu + j0))
                              : *((const float4*)(bvar + (j0 - DOUT)));
    #pragma unroll
    for (int i = 0; i < 4; i++) {
        int r = block_row + ty * 4 + i;
        if (r < M) {
            float4 v = make_float4(acc[i][0] + bias.x, acc[i][1] + bias.y,
                                   acc[i][2] + bias.z, acc[i][3] + bias.w);
            if (j0 < DOUT) *((float4*)(out_mu  + (size_t)r * DOUT + j0)) = v;
            else           *((float4*)(out_sig + (size_t)r * DOUT + (j0 - DOUT))) = v;
        }
    }
}

// ---- Wcat[k][0:64]=Wmu[k], Wcat[k][64:128]=Wvar[k] ----
__global__ void wcat_kernel(const float* __restrict__ Wmu, const float* __restrict__ Wvar,
                            float* __restrict__ Wcat) {
    int i = blockIdx.x * blockDim.x + threadIdx.x;
    int k = i >> 7, j = i & 127;
    Wcat[i] = (j < DOUT) ? Wmu[k * DOUT + j] : Wvar[k * DOUT + (j - DOUT)];
}

// ---- CSR aggregation: hout[i] = sum_{s in N(i)} hin[s]*dis[s]*dis[i] + hin[i]*dis[i]^2
//      optional +bias, optional relu.  32 threads (float4 lanes) per node. ----
template <bool RELU, bool BIAS>
__global__ __launch_bounds__(256) void agg_kernel(const int* __restrict__ rowptr_end,
                                                  const int* __restrict__ col,
                                                  const float* __restrict__ dis,
                                                  const float* __restrict__ hin,
                                                  float* __restrict__ hout,
                                                  const float* __restrict__ bias, int n) {
    int node = blockIdx.x * 8 + (threadIdx.x >> 5);
    if (node >= n) return;
    int lane = threadIdx.x & 31;
    int beg = (node == 0) ? 0 : rowptr_end[node - 1];
    int end = rowptr_end[node];
    float di = dis[node];
    const float4* hv = (const float4*)hin;

    float4 acc = hv[(size_t)node * 32 + lane];     // self-loop
    float sl = di * di;
    acc.x *= sl; acc.y *= sl; acc.z *= sl; acc.w *= sl;

    int e = beg;
    for (; e + 1 < end; e += 2) {
        int s0 = col[e], s1 = col[e + 1];
        float w0 = dis[s0] * di, w1 = dis[s1] * di;
        float4 v0 = hv[(size_t)s0 * 32 + lane];
        float4 v1 = hv[(size_t)s1 * 32 + lane];
        acc.x += v0.x * w0 + v1.x * w1;
        acc.y += v0.y * w0 + v1.y * w1;
        acc.z += v0.z * w0 + v1.z * w1;
        acc.w += v0.w * w0 + v1.w * w1;
    }
    if (e < end) {
        int s0 = col[e];
        float w0 = dis[s0] * di;
        float4 v0 = hv[(size_t)s0 * 32 + lane];
        acc.x += v0.x * w0; acc.y += v0.y * w0;
        acc.z += v0.z * w0; acc.w += v0.w * w0;
    }

    if (BIAS) {
        float4 b = ((const float4*)bias)[lane];
        acc.x += b.x; acc.y += b.y; acc.z += b.z; acc.w += b.w;
    }
    if (RELU) {
        acc.x = acc.x > 0.f ? acc.x : 0.f;
        acc.y = acc.y > 0.f ? acc.y : 0.f;
        acc.z = acc.z > 0.f ? acc.z : 0.f;
        acc.w = acc.w > 0.f ? acc.w : 0.f;
    }
    ((float4*)hout)[(size_t)node * 32 + lane] = acc;
}

extern "C" void kernel_launch(void* const* d_in, const int* in_sizes, int n_in,
                              void* d_out, int out_size, void* d_ws, size_t ws_size,
                              hipStream_t stream) {
    const float* x    = (const float*)d_in[0];
    const int*   ei   = (const int*)d_in[1];
    const float* W1   = (const float*)d_in[2];
    const float* b1   = (const float*)d_in[3];
    const float* Wmu  = (const float*)d_in[4];
    const float* bmu  = (const float*)d_in[5];
    const float* Wvar = (const float*)d_in[6];
    const float* bvar = (const float*)d_in[7];

    const int n = in_sizes[0] / 256;     // 100000
    const int E = in_sizes[1] / 2;       // 1600000
    const int* src = ei;
    const int* dst = ei + E;

    // workspace layout
    char* ws = (char*)d_ws;
    size_t off = 0;
    auto alloc = [&](size_t bytes) { void* p = ws + off; off = (off + bytes + 255) & ~(size_t)255; return p; };
    int*   deg    = (int*)  alloc((size_t)n * 4);
    float* dis    = (float*)alloc((size_t)n * 4);
    int*   rowptr = (int*)  alloc((size_t)n * 4);
    int*   bsum   = (int*)  alloc(512);
    int*   col    = (int*)  alloc((size_t)E * 4);
    float* Wcat   = (float*)alloc((size_t)HID * HID * 4);
    float* h      = (float*)alloc((size_t)n * HID * 4);   // layer1 pre-agg; later reused as agg2
    float* h1     = (float*)alloc((size_t)n * HID * 4);   // relu output
    float* agg2   = h;                                    // alias: h dead after agg1

    float* out_mu  = (float*)d_out;
    float* out_sig = (float*)d_out + (size_t)n * DOUT;

    const int nb_scan = (n + 1023) / 1024;

    hipMemsetAsync(deg, 0, (size_t)n * 4, stream);
    deg_kernel<<<(E + 255) / 256, 256, 0, stream>>>(dst, deg, E);
    dis_kernel<<<(n + 255) / 256, 256, 0, stream>>>(deg, dis, n);
    scan1_kernel<<<nb_scan, 256, 0, stream>>>(deg, rowptr, bsum, n);
    scan2_kernel<<<1, 64, 0, stream>>>(bsum, nb_scan);
    scan3_kernel<<<(n + 255) / 256, 256, 0, stream>>>(rowptr, bsum, n);
    fill_kernel<<<(E + 255) / 256, 256, 0, stream>>>(src, dst, rowptr, col, E);

    wcat_kernel<<<(HID * HID) / 256, 256, 0, stream>>>(Wmu, Wvar, Wcat);
    gemm_kernel<256><<<(n + 31) / 32, 256, 0, stream>>>(x, W1, h, n);
    agg_kernel<true, true><<<(n + 7) / 8, 256, 0, stream>>>(rowptr, col, dis, h, h1, b1, n);
    agg_kernel<false, false><<<(n + 7) / 8, 256, 0, stream>>>(rowptr, col, dis, h1, agg2, nullptr, n);
    gemm2_kernel<<<(n + 31) / 32, 256, 0, stream>>>(agg2, Wcat, bmu, bvar, out_mu, out_sig, n);
}

// Round 3
// 570.720 us; speedup vs baseline: 3.3026x; 1.3738x over previous
//
#include <hip/hip_runtime.h>

// VGAE GCN encoder: CSR aggregation + fp16 MFMA GEMMs.
// n=100000, f=256, hid=128, dout=64, E=1.6M (read from in_sizes).

#define HID 128
#define DOUT 64

typedef _Float16 half_t;
typedef half_t f16x2 __attribute__((ext_vector_type(2)));
typedef half_t f16x4 __attribute__((ext_vector_type(4)));
typedef half_t f16x8 __attribute__((ext_vector_type(8)));
typedef float  f32x4 __attribute__((ext_vector_type(4)));

// ---- degree histogram over dst ----
__global__ void deg_kernel(const int* __restrict__ dst, int* __restrict__ deg, int E) {
    int e = blockIdx.x * blockDim.x + threadIdx.x;
    if (e < E) atomicAdd(&deg[dst[e]], 1);
}

// dis = rsqrt(deg + 1)
__global__ void dis_kernel(const int* __restrict__ deg, float* __restrict__ dis, int n) {
    int i = blockIdx.x * blockDim.x + threadIdx.x;
    if (i < n) dis[i] = rsqrtf((float)deg[i] + 1.0f);
}

// ---- 3-kernel exclusive scan of deg -> rowptr ----
__global__ __launch_bounds__(256) void scan1_kernel(const int* __restrict__ deg,
                                                    int* __restrict__ rowptr,
                                                    int* __restrict__ bsum, int n) {
    __shared__ int s[256];
    int b = blockIdx.x, t = threadIdx.x;
    int base = b * 1024 + t * 4;
    int v0 = 0, v1 = 0, v2 = 0, v3 = 0;
    if (base + 0 < n) v0 = deg[base + 0];
    if (base + 1 < n) v1 = deg[base + 1];
    if (base + 2 < n) v2 = deg[base + 2];
    if (base + 3 < n) v3 = deg[base + 3];
    int tsum = v0 + v1 + v2 + v3;
    s[t] = tsum;
    __syncthreads();
    for (int off = 1; off < 256; off <<= 1) {
        int x = (t >= off) ? s[t - off] : 0;
        __syncthreads();
        s[t] += x;
        __syncthreads();
    }
    int excl = s[t] - tsum;
    if (base + 0 < n) rowptr[base + 0] = excl;
    if (base + 1 < n) rowptr[base + 1] = excl + v0;
    if (base + 2 < n) rowptr[base + 2] = excl + v0 + v1;
    if (base + 3 < n) rowptr[base + 3] = excl + v0 + v1 + v2;
    if (t == 255) bsum[b] = s[255];
}

__global__ void scan2_kernel(int* __restrict__ bsum, int nb) {
    if (threadIdx.x == 0 && blockIdx.x == 0) {
        int run = 0;
        for (int i = 0; i < nb; i++) { int t = bsum[i]; bsum[i] = run; run += t; }
    }
}

__global__ void scan3_kernel(int* __restrict__ rowptr, const int* __restrict__ bsum, int n) {
    int i = blockIdx.x * blockDim.x + threadIdx.x;
    if (i < n) rowptr[i] += bsum[i >> 10];
}

// ---- CSR fill: advances rowptr to inclusive form; col[pos] = src ----
__global__ void fill_kernel(const int* __restrict__ src, const int* __restrict__ dst,
                            int* __restrict__ rowptr, int* __restrict__ col, int E) {
    int e = blockIdx.x * blockDim.x + threadIdx.x;
    if (e < E) {
        int d = dst[e];
        int pos = atomicAdd(&rowptr[d], 1);
        col[pos] = src[e];
    }
}

// ---- weight prep: transpose + fp16 convert ----
// W1T[n][k] = W1[k][n], n<128, k<256
__global__ void w1t_kernel(const float* __restrict__ W1, half_t* __restrict__ W1T) {
    int i = blockIdx.x * blockDim.x + threadIdx.x;   // 256*128
    int k = i >> 7, n = i & 127;
    W1T[n * 256 + k] = (half_t)W1[i];
}
// WcatT[n][k]: n<64 -> Wmu[k][n], else Wvar[k][n-64]; k<128
__global__ void wcatt_kernel(const float* __restrict__ Wmu, const float* __restrict__ Wvar,
                             half_t* __restrict__ WcatT) {
    int i = blockIdx.x * blockDim.x + threadIdx.x;   // 128*128
    int k = i >> 7, n = i & 127;
    float v = (n < DOUT) ? Wmu[k * DOUT + n] : Wvar[k * DOUT + (n - DOUT)];
    WcatT[n * 128 + k] = (half_t)v;
}

// =====================================================================
// MFMA GEMM1: C[M,128](fp16) = A[M,256](fp32) @ W1T^T
// BM=128, BN=128, BK=64; 4 waves each 64x64 (4x4 of 16x16x32 tiles).
// LDS rows padded to 72 halfs (stride 36 dwords -> 2-way bank alias = free).
// =====================================================================
__global__ __launch_bounds__(256) void gemm1_mfma(const float* __restrict__ A,
                                                  const half_t* __restrict__ BT,
                                                  half_t* __restrict__ C, int M) {
    __shared__ half_t As[128][72];
    __shared__ half_t Bs[128][72];
    const int tid = threadIdx.x;
    const int block_row = blockIdx.x * 128;
    const int wave = tid >> 6, lane = tid & 63;
    const int wm = (wave & 1) * 64, wn = (wave >> 1) * 64;
    const int l16 = lane & 15, quad = lane >> 4;

    f32x4 acc[4][4] = {};

    for (int k0 = 0; k0 < 256; k0 += 64) {
        // stage A: 128 rows x 64 halfs, converting fp32->fp16
        #pragma unroll
        for (int i = 0; i < 8; i++) {
            int idx = tid + i * 256;                 // 0..2047
            int r = idx >> 4, c = idx & 15;          // 16 float4-chunks per row
            int row = block_row + r; row = row < M ? row : M - 1;
            float4 v = ((const float4*)(A + (size_t)row * 256 + k0))[c];
            f16x4 hv = { (half_t)v.x, (half_t)v.y, (half_t)v.z, (half_t)v.w };
            *(f16x4*)(&As[r][c * 4]) = hv;
        }
        // stage B: 128 n-rows x 64 k
        #pragma unroll
        for (int i = 0; i < 4; i++) {
            int idx = tid + i * 256;                 // 0..1023
            int nr = idx >> 3, kc = idx & 7;
            f16x8 b = *(const f16x8*)(BT + (size_t)nr * 256 + k0 + kc * 8);
            *(f16x8*)(&Bs[nr][kc * 8]) = b;
        }
        __syncthreads();

        #pragma unroll
        for (int ks = 0; ks < 2; ks++) {
            f16x8 af[4], bf[4];
            #pragma unroll
            for (int mt = 0; mt < 4; mt++)
                af[mt] = *(const f16x8*)(&As[wm + mt * 16 + l16][ks * 32 + quad * 8]);
            #pragma unroll
            for (int nt = 0; nt < 4; nt++)
                bf[nt] = *(const f16x8*)(&Bs[wn + nt * 16 + l16][ks * 32 + quad * 8]);
            #pragma unroll
            for (int mt = 0; mt < 4; mt++)
                #pragma unroll
                for (int nt = 0; nt < 4; nt++)
                    acc[mt][nt] = __builtin_amdgcn_mfma_f32_16x16x32_f16(af[mt], bf[nt], acc[mt][nt], 0, 0, 0);
        }
        __syncthreads();
    }

    #pragma unroll
    for (int mt = 0; mt < 4; mt++) {
        #pragma unroll
        for (int r = 0; r < 4; r++) {
            int row = block_row + wm + mt * 16 + quad * 4 + r;
            if (row < M) {
                #pragma unroll
                for (int nt = 0; nt < 4; nt++) {
                    int col = wn + nt * 16 + l16;
                    C[(size_t)row * 128 + col] = (half_t)acc[mt][nt][r];
                }
            }
        }
    }
}

// =====================================================================
// MFMA GEMM2: [mu|sig][M,128](fp32) = A[M,128](fp16) @ WcatT^T + bias
// =====================================================================
__global__ __launch_bounds__(256) void gemm2_mfma(const half_t* __restrict__ A,
                                                  const half_t* __restrict__ BT,
                                                  const float* __restrict__ bmu,
                                                  const float* __restrict__ bvar,
                                                  float* __restrict__ out_mu,
                                                  float* __restrict__ out_sig, int M) {
    __shared__ half_t As[128][72];
    __shared__ half_t Bs[128][72];
    const int tid = threadIdx.x;
    const int block_row = blockIdx.x * 128;
    const int wave = tid >> 6, lane = tid & 63;
    const int wm = (wave & 1) * 64, wn = (wave >> 1) * 64;
    const int l16 = lane & 15, quad = lane >> 4;

    f32x4 acc[4][4] = {};

    for (int k0 = 0; k0 < 128; k0 += 64) {
        #pragma unroll
        for (int i = 0; i < 4; i++) {
            int idx = tid + i * 256;                 // 0..1023
            int r = idx >> 3, kc = idx & 7;
            int row = block_row + r; row = row < M ? row : M - 1;
            f16x8 a = *(const f16x8*)(A + (size_t)row * 128 + k0 + kc * 8);
            *(f16x8*)(&As[r][kc * 8]) = a;
        }
        #pragma unroll
        for (int i = 0; i < 4; i++) {
            int idx = tid + i * 256;
            int nr = idx >> 3, kc = idx & 7;
            f16x8 b = *(const f16x8*)(BT + (size_t)nr * 128 + k0 + kc * 8);
            *(f16x8*)(&Bs[nr][kc * 8]) = b;
        }
        __syncthreads();

        #pragma unroll
        for (int ks = 0; ks < 2; ks++) {
            f16x8 af[4], bf[4];
            #pragma unroll
            for (int mt = 0; mt < 4; mt++)
                af[mt] = *(const f16x8*)(&As[wm + mt * 16 + l16][ks * 32 + quad * 8]);
            #pragma unroll
            for (int nt = 0; nt < 4; nt++)
                bf[nt] = *(const f16x8*)(&Bs[wn + nt * 16 + l16][ks * 32 + quad * 8]);
            #pragma unroll
            for (int mt = 0; mt < 4; mt++)
                #pragma unroll
                for (int nt = 0; nt < 4; nt++)
                    acc[mt][nt] = __builtin_amdgcn_mfma_f32_16x16x32_f16(af[mt], bf[nt], acc[mt][nt], 0, 0, 0);
        }
        __syncthreads();
    }

    float bias[4];
    int cols[4];
    #pragma unroll
    for (int nt = 0; nt < 4; nt++) {
        int col = wn + nt * 16 + l16;
        cols[nt] = col;
        bias[nt] = (col < DOUT) ? bmu[col] : bvar[col - DOUT];
    }

    #pragma unroll
    for (int mt = 0; mt < 4; mt++) {
        #pragma unroll
        for (int r = 0; r < 4; r++) {
            int row = block_row + wm + mt * 16 + quad * 4 + r;
            if (row < M) {
                #pragma unroll
                for (int nt = 0; nt < 4; nt++) {
                    int col = cols[nt];
                    float v = acc[mt][nt][r] + bias[nt];
                    if (col < DOUT) out_mu[(size_t)row * DOUT + col] = v;
                    else            out_sig[(size_t)row * DOUT + (col - DOUT)] = v;
                }
            }
        }
    }
}

// ---- CSR aggregation (fp16 features, fp32 accumulate):
// hout[i] = sum_{s in N(i)} hin[s]*dis[s]*dis[i] + hin[i]*dis[i]^2 (+bias)(relu)
// 32 lanes (f16x4 = 8B each) per node. ----
template <bool RELU, bool BIAS>
__global__ __launch_bounds__(256) void agg_kernel(const int* __restrict__ rowptr_end,
                                                  const int* __restrict__ col,
                                                  const float* __restrict__ dis,
                                                  const half_t* __restrict__ hin,
                                                  half_t* __restrict__ hout,
                                                  const float* __restrict__ bias, int n) {
    int node = blockIdx.x * 8 + (threadIdx.x >> 5);
    if (node >= n) return;
    int lane = threadIdx.x & 31;
    int beg = (node == 0) ? 0 : rowptr_end[node - 1];
    int end = rowptr_end[node];
    float di = dis[node];
    const f16x4* hv = (const f16x4*)hin;

    f16x4 sv = hv[(size_t)node * 32 + lane];
    float sl = di * di;
    float ax = (float)sv[0] * sl, ay = (float)sv[1] * sl,
          az = (float)sv[2] * sl, aw = (float)sv[3] * sl;

    int e = beg;
    for (; e + 1 < end; e += 2) {
        int s0 = col[e], s1 = col[e + 1];
        float w0 = dis[s0] * di, w1 = dis[s1] * di;
        f16x4 v0 = hv[(size_t)s0 * 32 + lane];
        f16x4 v1 = hv[(size_t)s1 * 32 + lane];
        ax += (float)v0[0] * w0 + (float)v1[0] * w1;
        ay += (float)v0[1] * w0 + (float)v1[1] * w1;
        az += (float)v0[2] * w0 + (float)v1[2] * w1;
        aw += (float)v0[3] * w0 + (float)v1[3] * w1;
    }
    if (e < end) {
        int s0 = col[e];
        float w0 = dis[s0] * di;
        f16x4 v0 = hv[(size_t)s0 * 32 + lane];
        ax += (float)v0[0] * w0; ay += (float)v0[1] * w0;
        az += (float)v0[2] * w0; aw += (float)v0[3] * w0;
    }

    if (BIAS) {
        const float4 b = ((const float4*)bias)[lane];
        ax += b.x; ay += b.y; az += b.z; aw += b.w;
    }
    if (RELU) {
        ax = ax > 0.f ? ax : 0.f;
        ay = ay > 0.f ? ay : 0.f;
        az = az > 0.f ? az : 0.f;
        aw = aw > 0.f ? aw : 0.f;
    }
    f16x4 o = { (half_t)ax, (half_t)ay, (half_t)az, (half_t)aw };
    ((f16x4*)hout)[(size_t)node * 32 + lane] = o;
}

extern "C" void kernel_launch(void* const* d_in, const int* in_sizes, int n_in,
                              void* d_out, int out_size, void* d_ws, size_t ws_size,
                              hipStream_t stream) {
    const float* x    = (const float*)d_in[0];
    const int*   ei   = (const int*)d_in[1];
    const float* W1   = (const float*)d_in[2];
    const float* b1   = (const float*)d_in[3];
    const float* Wmu  = (const float*)d_in[4];
    const float* bmu  = (const float*)d_in[5];
    const float* Wvar = (const float*)d_in[6];
    const float* bvar = (const float*)d_in[7];

    const int n = in_sizes[0] / 256;     // 100000
    const int E = in_sizes[1] / 2;       // 1600000
    const int* src = ei;
    const int* dst = ei + E;

    char* ws = (char*)d_ws;
    size_t off = 0;
    auto alloc = [&](size_t bytes) { void* p = ws + off; off = (off + bytes + 255) & ~(size_t)255; return p; };
    int*    deg    = (int*)   alloc((size_t)n * 4);
    float*  dis    = (float*) alloc((size_t)n * 4);
    int*    rowptr = (int*)   alloc((size_t)n * 4);
    int*    bsum   = (int*)   alloc(512);
    int*    col    = (int*)   alloc((size_t)E * 4);
    half_t* W1T    = (half_t*)alloc((size_t)256 * HID * 2);
    half_t* WcatT  = (half_t*)alloc((size_t)HID * HID * 2);
    half_t* h      = (half_t*)alloc((size_t)n * HID * 2);  // gemm1 out; reused as agg2
    half_t* h1     = (half_t*)alloc((size_t)n * HID * 2);  // relu output
    half_t* agg2   = h;                                    // alias: h dead after agg1

    float* out_mu  = (float*)d_out;
    float* out_sig = (float*)d_out + (size_t)n * DOUT;

    const int nb_scan = (n + 1023) / 1024;

    hipMemsetAsync(deg, 0, (size_t)n * 4, stream);
    deg_kernel<<<(E + 255) / 256, 256, 0, stream>>>(dst, deg, E);
    dis_kernel<<<(n + 255) / 256, 256, 0, stream>>>(deg, dis, n);
    scan1_kernel<<<nb_scan, 256, 0, stream>>>(deg, rowptr, bsum, n);
    scan2_kernel<<<1, 64, 0, stream>>>(bsum, nb_scan);
    scan3_kernel<<<(n + 255) / 256, 256, 0, stream>>>(rowptr, bsum, n);
    fill_kernel<<<(E + 255) / 256, 256, 0, stream>>>(src, dst, rowptr, col, E);

    w1t_kernel<<<(256 * HID) / 256, 256, 0, stream>>>(W1, W1T);
    wcatt_kernel<<<(HID * HID) / 256, 256, 0, stream>>>(Wmu, Wvar, WcatT);

    gemm1_mfma<<<(n + 127) / 128, 256, 0, stream>>>(x, W1T, h, n);
    agg_kernel<true, true><<<(n + 7) / 8, 256, 0, stream>>>(rowptr, col, dis, h, h1, b1, n);
    agg_kernel<false, false><<<(n + 7) / 8, 256, 0, stream>>>(rowptr, col, dis, h1, agg2, nullptr, n);
    gemm2_mfma<<<(n + 127) / 128, 256, 0, stream>>>(agg2, WcatT, bmu, bvar, out_mu, out_sig, n);
}

// Round 4
// 446.451 us; speedup vs baseline: 4.2219x; 1.2783x over previous
//
#include <hip/hip_runtime.h>

// VGAE GCN encoder: radix-binned CSR build + CSR gather aggregation + fp16 MFMA GEMMs.
// n=100000, f=256, hid=128, dout=64, E=1.6M (read from in_sizes).

#define HID 128
#define DOUT 64
#define NB_SHIFT 8          // 256 nodes per bucket
#define CHUNK 8192          // edges per binning block
#define MAXNB 400           // max buckets (n <= 102400)

typedef _Float16 half_t;
typedef half_t f16x4 __attribute__((ext_vector_type(4)));
typedef half_t f16x8 __attribute__((ext_vector_type(8)));
typedef float  f32x4 __attribute__((ext_vector_type(4)));

// ==================== CSR build (two-level radix, no global write-amp) ====================

// counts[bucket * nblocks + block] = #edges in this block's chunk landing in bucket
__global__ __launch_bounds__(256) void bincount_kernel(const int* __restrict__ dst,
                                                       int* __restrict__ counts,
                                                       int E, int nblocks, int NB) {
    __shared__ int hist[MAXNB];
    const int b = blockIdx.x;
    for (int t = threadIdx.x; t < NB; t += 256) hist[t] = 0;
    __syncthreads();
    const int beg = b * CHUNK;
    const int end = min(E, beg + CHUNK);
    for (int e = beg + threadIdx.x; e < end; e += 256)
        atomicAdd(&hist[dst[e] >> NB_SHIFT], 1);
    __syncthreads();
    for (int t = threadIdx.x; t < NB; t += 256)
        counts[t * nblocks + b] = hist[t];
}

// ---- 3-kernel exclusive scan over a flat int array (1024 elems/block) ----
__global__ __launch_bounds__(256) void scan1_kernel(const int* __restrict__ in,
                                                    int* __restrict__ out,
                                                    int* __restrict__ bsum, int n) {
    __shared__ int s[256];
    int b = blockIdx.x, t = threadIdx.x;
    int base = b * 1024 + t * 4;
    int v0 = 0, v1 = 0, v2 = 0, v3 = 0;
    if (base + 0 < n) v0 = in[base + 0];
    if (base + 1 < n) v1 = in[base + 1];
    if (base + 2 < n) v2 = in[base + 2];
    if (base + 3 < n) v3 = in[base + 3];
    int tsum = v0 + v1 + v2 + v3;
    s[t] = tsum;
    __syncthreads();
    for (int off = 1; off < 256; off <<= 1) {
        int x = (t >= off) ? s[t - off] : 0;
        __syncthreads();
        s[t] += x;
        __syncthreads();
    }
    int excl = s[t] - tsum;
    if (base + 0 < n) out[base + 0] = excl;
    if (base + 1 < n) out[base + 1] = excl + v0;
    if (base + 2 < n) out[base + 2] = excl + v0 + v1;
    if (base + 3 < n) out[base + 3] = excl + v0 + v1 + v2;
    if (t == 255) bsum[b] = s[255];
}

__global__ void scan2_kernel(int* __restrict__ bsum, int nb) {
    if (threadIdx.x == 0 && blockIdx.x == 0) {
        int run = 0;
        for (int i = 0; i < nb; i++) { int t = bsum[i]; bsum[i] = run; run += t; }
    }
}

__global__ void scan3_kernel(int* __restrict__ out, const int* __restrict__ bsum, int n) {
    int i = blockIdx.x * blockDim.x + threadIdx.x;
    if (i < n) out[i] += bsum[i >> 10];
}

// scatter edges into bucket-major binned array; each (bucket,block) range is
// contiguous and written only by this block -> write amplification ~1.
__global__ __launch_bounds__(256) void binscatter_kernel(const int* __restrict__ src,
                                                         const int* __restrict__ dst,
                                                         const int* __restrict__ offsets,
                                                         int2* __restrict__ binned,
                                                         int E, int nblocks, int NB) {
    __shared__ int cur[MAXNB];
    const int b = blockIdx.x;
    for (int t = threadIdx.x; t < NB; t += 256) cur[t] = offsets[t * nblocks + b];
    __syncthreads();
    const int beg = b * CHUNK;
    const int end = min(E, beg + CHUNK);
    for (int e = beg + threadIdx.x; e < end; e += 256) {
        int d = dst[e], s = src[e];
        int pos = atomicAdd(&cur[d >> NB_SHIFT], 1);
        binned[pos] = make_int2(s, d);
    }
}

// one WG per bucket: local degree hist -> local scan -> dis/rowptr_end (coalesced)
// -> place col within the bucket's 16KB window (single-WG locality).
__global__ __launch_bounds__(256) void csrbuild_kernel(const int2* __restrict__ binned,
                                                       const int* __restrict__ offsets,
                                                       int* __restrict__ rowptr_end,
                                                       int* __restrict__ colA,
                                                       float* __restrict__ dis,
                                                       int E, int nblocks, int NB, int n) {
    __shared__ int deg[256];
    __shared__ int sc[256];
    __shared__ int cur[256];
    const int b = blockIdx.x;
    const int t = threadIdx.x;
    const int base = offsets[b * nblocks];
    const int bend = (b + 1 < NB) ? offsets[(b + 1) * nblocks] : E;

    deg[t] = 0;
    __syncthreads();
    for (int e = base + t; e < bend; e += 256)
        atomicAdd(&deg[binned[e].y & 255], 1);
    __syncthreads();

    int v = deg[t];
    sc[t] = v;
    __syncthreads();
    for (int off = 1; off < 256; off <<= 1) {
        int x = (t >= off) ? sc[t - off] : 0;
        __syncthreads();
        sc[t] += x;
        __syncthreads();
    }
    int incl = sc[t];
    int node = (b << NB_SHIFT) + t;
    if (node < n) {
        rowptr_end[node] = base + incl;
        dis[node] = rsqrtf((float)v + 1.0f);
    }
    cur[t] = base + incl - v;
    __syncthreads();

    for (int e = base + t; e < bend; e += 256) {
        int2 sd = binned[e];
        int pos = atomicAdd(&cur[sd.y & 255], 1);
        colA[pos] = sd.x;
    }
}

// ==================== weight prep ====================
// W1T[nn][k] = W1[k][nn], nn<128, k<256
__global__ void w1t_kernel(const float* __restrict__ W1, half_t* __restrict__ W1T) {
    int i = blockIdx.x * blockDim.x + threadIdx.x;   // 256*128
    int k = i >> 7, nn = i & 127;
    W1T[nn * 256 + k] = (half_t)W1[i];
}
// WcatT[nn][k]: nn<64 -> Wmu[k][nn], else Wvar[k][nn-64]; k<128
__global__ void wcatt_kernel(const float* __restrict__ Wmu, const float* __restrict__ Wvar,
                             half_t* __restrict__ WcatT) {
    int i = blockIdx.x * blockDim.x + threadIdx.x;   // 128*128
    int k = i >> 7, nn = i & 127;
    float v = (nn < DOUT) ? Wmu[k * DOUT + nn] : Wvar[k * DOUT + (nn - DOUT)];
    WcatT[nn * 128 + k] = (half_t)v;
}

// ==================== MFMA GEMMs ====================
// GEMM1: C[M,128](fp16) = A[M,256](fp32) @ W1T^T.  BM=BN=128, BK=64, 4 waves.
__global__ __launch_bounds__(256) void gemm1_mfma(const float* __restrict__ A,
                                                  const half_t* __restrict__ BT,
                                                  half_t* __restrict__ C, int M) {
    __shared__ half_t As[128][72];
    __shared__ half_t Bs[128][72];
    const int tid = threadIdx.x;
    const int block_row = blockIdx.x * 128;
    const int wave = tid >> 6, lane = tid & 63;
    const int wm = (wave & 1) * 64, wn = (wave >> 1) * 64;
    const int l16 = lane & 15, quad = lane >> 4;

    f32x4 acc[4][4] = {};

    for (int k0 = 0; k0 < 256; k0 += 64) {
        #pragma unroll
        for (int i = 0; i < 8; i++) {
            int idx = tid + i * 256;
            int r = idx >> 4, c = idx & 15;
            int row = block_row + r; row = row < M ? row : M - 1;
            float4 v = ((const float4*)(A + (size_t)row * 256 + k0))[c];
            f16x4 hv = { (half_t)v.x, (half_t)v.y, (half_t)v.z, (half_t)v.w };
            *(f16x4*)(&As[r][c * 4]) = hv;
        }
        #pragma unroll
        for (int i = 0; i < 4; i++) {
            int idx = tid + i * 256;
            int nr = idx >> 3, kc = idx & 7;
            f16x8 bvv = *(const f16x8*)(BT + (size_t)nr * 256 + k0 + kc * 8);
            *(f16x8*)(&Bs[nr][kc * 8]) = bvv;
        }
        __syncthreads();

        #pragma unroll
        for (int ks = 0; ks < 2; ks++) {
            f16x8 af[4], bf[4];
            #pragma unroll
            for (int mt = 0; mt < 4; mt++)
                af[mt] = *(const f16x8*)(&As[wm + mt * 16 + l16][ks * 32 + quad * 8]);
            #pragma unroll
            for (int nt = 0; nt < 4; nt++)
                bf[nt] = *(const f16x8*)(&Bs[wn + nt * 16 + l16][ks * 32 + quad * 8]);
            #pragma unroll
            for (int mt = 0; mt < 4; mt++)
                #pragma unroll
                for (int nt = 0; nt < 4; nt++)
                    acc[mt][nt] = __builtin_amdgcn_mfma_f32_16x16x32_f16(af[mt], bf[nt], acc[mt][nt], 0, 0, 0);
        }
        __syncthreads();
    }

    #pragma unroll
    for (int mt = 0; mt < 4; mt++) {
        #pragma unroll
        for (int r = 0; r < 4; r++) {
            int row = block_row + wm + mt * 16 + quad * 4 + r;
            if (row < M) {
                #pragma unroll
                for (int nt = 0; nt < 4; nt++) {
                    int col = wn + nt * 16 + l16;
                    C[(size_t)row * 128 + col] = (half_t)acc[mt][nt][r];
                }
            }
        }
    }
}

// GEMM2: [mu|sig][M,64](fp32) = A[M,128](fp16) @ WcatT^T + bias
__global__ __launch_bounds__(256) void gemm2_mfma(const half_t* __restrict__ A,
                                                  const half_t* __restrict__ BT,
                                                  const float* __restrict__ bmu,
                                                  const float* __restrict__ bvar,
                                                  float* __restrict__ out_mu,
                                                  float* __restrict__ out_sig, int M) {
    __shared__ half_t As[128][72];
    __shared__ half_t Bs[128][72];
    const int tid = threadIdx.x;
    const int block_row = blockIdx.x * 128;
    const int wave = tid >> 6, lane = tid & 63;
    const int wm = (wave & 1) * 64, wn = (wave >> 1) * 64;
    const int l16 = lane & 15, quad = lane >> 4;

    f32x4 acc[4][4] = {};

    for (int k0 = 0; k0 < 128; k0 += 64) {
        #pragma unroll
        for (int i = 0; i < 4; i++) {
            int idx = tid + i * 256;
            int r = idx >> 3, kc = idx & 7;
            int row = block_row + r; row = row < M ? row : M - 1;
            f16x8 a = *(const f16x8*)(A + (size_t)row * 128 + k0 + kc * 8);
            *(f16x8*)(&As[r][kc * 8]) = a;
        }
        #pragma unroll
        for (int i = 0; i < 4; i++) {
            int idx = tid + i * 256;
            int nr = idx >> 3, kc = idx & 7;
            f16x8 bvv = *(const f16x8*)(BT + (size_t)nr * 128 + k0 + kc * 8);
            *(f16x8*)(&Bs[nr][kc * 8]) = bvv;
        }
        __syncthreads();

        #pragma unroll
        for (int ks = 0; ks < 2; ks++) {
            f16x8 af[4], bf[4];
            #pragma unroll
            for (int mt = 0; mt < 4; mt++)
                af[mt] = *(const f16x8*)(&As[wm + mt * 16 + l16][ks * 32 + quad * 8]);
            #pragma unroll
            for (int nt = 0; nt < 4; nt++)
                bf[nt] = *(const f16x8*)(&Bs[wn + nt * 16 + l16][ks * 32 + quad * 8]);
            #pragma unroll
            for (int mt = 0; mt < 4; mt++)
                #pragma unroll
                for (int nt = 0; nt < 4; nt++)
                    acc[mt][nt] = __builtin_amdgcn_mfma_f32_16x16x32_f16(af[mt], bf[nt], acc[mt][nt], 0, 0, 0);
        }
        __syncthreads();
    }

    float bias[4];
    int cols[4];
    #pragma unroll
    for (int nt = 0; nt < 4; nt++) {
        int col = wn + nt * 16 + l16;
        cols[nt] = col;
        bias[nt] = (col < DOUT) ? bmu[col] : bvar[col - DOUT];
    }

    #pragma unroll
    for (int mt = 0; mt < 4; mt++) {
        #pragma unroll
        for (int r = 0; r < 4; r++) {
            int row = block_row + wm + mt * 16 + quad * 4 + r;
            if (row < M) {
                #pragma unroll
                for (int nt = 0; nt < 4; nt++) {
                    int col = cols[nt];
                    float v = acc[mt][nt][r] + bias[nt];
                    if (col < DOUT) out_mu[(size_t)row * DOUT + col] = v;
                    else            out_sig[(size_t)row * DOUT + (col - DOUT)] = v;
                }
            }
        }
    }
}

// ==================== CSR aggregation (fp16 features, fp32 accumulate) ====================
template <bool RELU, bool BIAS>
__global__ __launch_bounds__(256) void agg_kernel(const int* __restrict__ rowptr_end,
                                                  const int* __restrict__ col,
                                                  const float* __restrict__ dis,
                                                  const half_t* __restrict__ hin,
                                                  half_t* __restrict__ hout,
                                                  const float* __restrict__ bias, int n) {
    int node = blockIdx.x * 8 + (threadIdx.x >> 5);
    if (node >= n) return;
    int lane = threadIdx.x & 31;
    int beg = (node == 0) ? 0 : rowptr_end[node - 1];
    int end = rowptr_end[node];
    float di = dis[node];
    const f16x4* hv = (const f16x4*)hin;

    f16x4 sv = hv[(size_t)node * 32 + lane];
    float sl = di * di;
    float ax = (float)sv[0] * sl, ay = (float)sv[1] * sl,
          az = (float)sv[2] * sl, aw = (float)sv[3] * sl;

    int e = beg;
    for (; e + 1 < end; e += 2) {
        int s0 = col[e], s1 = col[e + 1];
        float w0 = dis[s0] * di, w1 = dis[s1] * di;
        f16x4 v0 = hv[(size_t)s0 * 32 + lane];
        f16x4 v1 = hv[(size_t)s1 * 32 + lane];
        ax += (float)v0[0] * w0 + (float)v1[0] * w1;
        ay += (float)v0[1] * w0 + (float)v1[1] * w1;
        az += (float)v0[2] * w0 + (float)v1[2] * w1;
        aw += (float)v0[3] * w0 + (float)v1[3] * w1;
    }
    if (e < end) {
        int s0 = col[e];
        float w0 = dis[s0] * di;
        f16x4 v0 = hv[(size_t)s0 * 32 + lane];
        ax += (float)v0[0] * w0; ay += (float)v0[1] * w0;
        az += (float)v0[2] * w0; aw += (float)v0[3] * w0;
    }

    if (BIAS) {
        const float4 b = ((const float4*)bias)[lane];
        ax += b.x; ay += b.y; az += b.z; aw += b.w;
    }
    if (RELU) {
        ax = ax > 0.f ? ax : 0.f;
        ay = ay > 0.f ? ay : 0.f;
        az = az > 0.f ? az : 0.f;
        aw = aw > 0.f ? aw : 0.f;
    }
    f16x4 o = { (half_t)ax, (half_t)ay, (half_t)az, (half_t)aw };
    ((f16x4*)hout)[(size_t)node * 32 + lane] = o;
}

extern "C" void kernel_launch(void* const* d_in, const int* in_sizes, int n_in,
                              void* d_out, int out_size, void* d_ws, size_t ws_size,
                              hipStream_t stream) {
    const float* x    = (const float*)d_in[0];
    const int*   ei   = (const int*)d_in[1];
    const float* W1   = (const float*)d_in[2];
    const float* b1   = (const float*)d_in[3];
    const float* Wmu  = (const float*)d_in[4];
    const float* bmu  = (const float*)d_in[5];
    const float* Wvar = (const float*)d_in[6];
    const float* bvar = (const float*)d_in[7];

    const int n = in_sizes[0] / 256;     // 100000
    const int E = in_sizes[1] / 2;       // 1600000
    const int* src = ei;
    const int* dst = ei + E;

    const int NB      = (n + 255) >> NB_SHIFT;       // 391 buckets
    const int nblocks = (E + CHUNK - 1) / CHUNK;     // 196 chunks
    const int flat    = NB * nblocks;                // counts/offsets size
    const int nb_scan = (flat + 1023) / 1024;

    char* ws = (char*)d_ws;
    size_t off = 0;
    auto alloc = [&](size_t bytes) { void* p = ws + off; off = (off + bytes + 255) & ~(size_t)255; return p; };
    float*  dis     = (float*) alloc((size_t)n * 4);
    int*    rowptr  = (int*)   alloc((size_t)n * 4);      // inclusive end per node
    int*    counts  = (int*)   alloc((size_t)flat * 4);
    int*    offsets = (int*)   alloc((size_t)flat * 4);
    int*    bsum    = (int*)   alloc((size_t)nb_scan * 4 + 256);
    int2*   binned  = (int2*)  alloc((size_t)E * 8);
    int*    col     = (int*)   alloc((size_t)E * 4);
    half_t* W1T     = (half_t*)alloc((size_t)256 * HID * 2);
    half_t* WcatT   = (half_t*)alloc((size_t)HID * HID * 2);
    half_t* h       = (half_t*)alloc((size_t)n * HID * 2);  // gemm1 out; reused as agg2
    half_t* h1      = (half_t*)alloc((size_t)n * HID * 2);  // relu output
    half_t* agg2    = h;                                    // alias: h dead after agg1

    float* out_mu  = (float*)d_out;
    float* out_sig = (float*)d_out + (size_t)n * DOUT;

    // CSR build
    bincount_kernel<<<nblocks, 256, 0, stream>>>(dst, counts, E, nblocks, NB);
    scan1_kernel<<<nb_scan, 256, 0, stream>>>(counts, offsets, bsum, flat);
    scan2_kernel<<<1, 64, 0, stream>>>(bsum, nb_scan);
    scan3_kernel<<<(flat + 255) / 256, 256, 0, stream>>>(offsets, bsum, flat);
    binscatter_kernel<<<nblocks, 256, 0, stream>>>(src, dst, offsets, binned, E, nblocks, NB);
    csrbuild_kernel<<<NB, 256, 0, stream>>>(binned, offsets, rowptr, col, dis, E, nblocks, NB, n);

    // weights
    w1t_kernel<<<(256 * HID) / 256, 256, 0, stream>>>(W1, W1T);
    wcatt_kernel<<<(HID * HID) / 256, 256, 0, stream>>>(Wmu, Wvar, WcatT);

    // dense + sparse pipeline
    gemm1_mfma<<<(n + 127) / 128, 256, 0, stream>>>(x, W1T, h, n);
    agg_kernel<true, true><<<(n + 7) / 8, 256, 0, stream>>>(rowptr, col, dis, h, h1, b1, n);
    agg_kernel<false, false><<<(n + 7) / 8, 256, 0, stream>>>(rowptr, col, dis, h1, agg2, nullptr, n);
    gemm2_mfma<<<(n + 127) / 128, 256, 0, stream>>>(agg2, WcatT, bmu, bvar, out_mu, out_sig, n);
}

// Round 5
// 398.569 us; speedup vs baseline: 4.7291x; 1.1201x over previous
//
#include <hip/hip_runtime.h>

// VGAE GCN encoder: radix-binned CSR build + pre-scaled gather aggregation
// + register-pipelined fp16 MFMA GEMMs.
// n=100000, f=256, hid=128, dout=64, E=1.6M (read from in_sizes).
//
// Algebra: norm-folded features.  hs = (X@W1)*dis  (fp16);
//   agg1: acc_i = hs_i + sum_{s in N(i)} hs_s ;  h1s_i = relu(dis_i*acc_i + b1)*dis_i
//   agg2: agg2_i = dis_i*(h1s_i + sum h1s_s)    ;  out = agg2 @ [Wmu|Wvar] + bias
// One random gather per edge, no per-edge weights.

#define HID 128
#define DOUT 64
#define NB_SHIFT 8          // 256 nodes per bucket
#define CHUNK 8192          // edges per binning block
#define MAXNB 400           // max buckets (n <= 102400)

typedef _Float16 half_t;
typedef half_t f16x4 __attribute__((ext_vector_type(4)));
typedef half_t f16x8 __attribute__((ext_vector_type(8)));
typedef float  f32x4 __attribute__((ext_vector_type(4)));

// ==================== CSR build (two-level radix, no global write-amp) ====================

__global__ __launch_bounds__(256) void bincount_kernel(const int* __restrict__ dst,
                                                       int* __restrict__ counts,
                                                       int E, int nblocks, int NB) {
    __shared__ int hist[MAXNB];
    const int b = blockIdx.x;
    for (int t = threadIdx.x; t < NB; t += 256) hist[t] = 0;
    __syncthreads();
    const int beg = b * CHUNK;
    const int end = min(E, beg + CHUNK);
    for (int e = beg + threadIdx.x; e < end; e += 256)
        atomicAdd(&hist[dst[e] >> NB_SHIFT], 1);
    __syncthreads();
    for (int t = threadIdx.x; t < NB; t += 256)
        counts[t * nblocks + b] = hist[t];
}

__global__ __launch_bounds__(256) void scan1_kernel(const int* __restrict__ in,
                                                    int* __restrict__ out,
                                                    int* __restrict__ bsum, int n) {
    __shared__ int s[256];
    int b = blockIdx.x, t = threadIdx.x;
    int base = b * 1024 + t * 4;
    int v0 = 0, v1 = 0, v2 = 0, v3 = 0;
    if (base + 0 < n) v0 = in[base + 0];
    if (base + 1 < n) v1 = in[base + 1];
    if (base + 2 < n) v2 = in[base + 2];
    if (base + 3 < n) v3 = in[base + 3];
    int tsum = v0 + v1 + v2 + v3;
    s[t] = tsum;
    __syncthreads();
    for (int off = 1; off < 256; off <<= 1) {
        int x = (t >= off) ? s[t - off] : 0;
        __syncthreads();
        s[t] += x;
        __syncthreads();
    }
    int excl = s[t] - tsum;
    if (base + 0 < n) out[base + 0] = excl;
    if (base + 1 < n) out[base + 1] = excl + v0;
    if (base + 2 < n) out[base + 2] = excl + v0 + v1;
    if (base + 3 < n) out[base + 3] = excl + v0 + v1 + v2;
    if (t == 255) bsum[b] = s[255];
}

__global__ void scan2_kernel(int* __restrict__ bsum, int nb) {
    if (threadIdx.x == 0 && blockIdx.x == 0) {
        int run = 0;
        for (int i = 0; i < nb; i++) { int t = bsum[i]; bsum[i] = run; run += t; }
    }
}

__global__ void scan3_kernel(int* __restrict__ out, const int* __restrict__ bsum, int n) {
    int i = blockIdx.x * blockDim.x + threadIdx.x;
    if (i < n) out[i] += bsum[i >> 10];
}

__global__ __launch_bounds__(256) void binscatter_kernel(const int* __restrict__ src,
                                                         const int* __restrict__ dst,
                                                         const int* __restrict__ offsets,
                                                         int2* __restrict__ binned,
                                                         int E, int nblocks, int NB) {
    __shared__ int cur[MAXNB];
    const int b = blockIdx.x;
    for (int t = threadIdx.x; t < NB; t += 256) cur[t] = offsets[t * nblocks + b];
    __syncthreads();
    const int beg = b * CHUNK;
    const int end = min(E, beg + CHUNK);
    for (int e = beg + threadIdx.x; e < end; e += 256) {
        int d = dst[e], s = src[e];
        int pos = atomicAdd(&cur[d >> NB_SHIFT], 1);
        binned[pos] = make_int2(s, d);
    }
}

__global__ __launch_bounds__(256) void csrbuild_kernel(const int2* __restrict__ binned,
                                                       const int* __restrict__ offsets,
                                                       int* __restrict__ rowptr_end,
                                                       int* __restrict__ colA,
                                                       float* __restrict__ dis,
                                                       int E, int nblocks, int NB, int n) {
    __shared__ int deg[256];
    __shared__ int sc[256];
    __shared__ int cur[256];
    const int b = blockIdx.x;
    const int t = threadIdx.x;
    const int base = offsets[b * nblocks];
    const int bend = (b + 1 < NB) ? offsets[(b + 1) * nblocks] : E;

    deg[t] = 0;
    __syncthreads();
    for (int e = base + t; e < bend; e += 256)
        atomicAdd(&deg[binned[e].y & 255], 1);
    __syncthreads();

    int v = deg[t];
    sc[t] = v;
    __syncthreads();
    for (int off = 1; off < 256; off <<= 1) {
        int x = (t >= off) ? sc[t - off] : 0;
        __syncthreads();
        sc[t] += x;
        __syncthreads();
    }
    int incl = sc[t];
    int node = (b << NB_SHIFT) + t;
    if (node < n) {
        rowptr_end[node] = base + incl;
        dis[node] = rsqrtf((float)v + 1.0f);
    }
    cur[t] = base + incl - v;
    __syncthreads();

    for (int e = base + t; e < bend; e += 256) {
        int2 sd = binned[e];
        int pos = atomicAdd(&cur[sd.y & 255], 1);
        colA[pos] = sd.x;
    }
}

// ==================== weight prep ====================
__global__ void w1t_kernel(const float* __restrict__ W1, half_t* __restrict__ W1T) {
    int i = blockIdx.x * blockDim.x + threadIdx.x;   // 256*128
    int k = i >> 7, nn = i & 127;
    W1T[nn * 256 + k] = (half_t)W1[i];
}
__global__ void wcatt_kernel(const float* __restrict__ Wmu, const float* __restrict__ Wvar,
                             half_t* __restrict__ WcatT) {
    int i = blockIdx.x * blockDim.x + threadIdx.x;   // 128*128
    int k = i >> 7, nn = i & 127;
    float v = (nn < DOUT) ? Wmu[k * DOUT + nn] : Wvar[k * DOUT + (nn - DOUT)];
    WcatT[nn * 128 + k] = (half_t)v;
}

// ==================== MFMA GEMM1 (register-prefetch pipelined) ====================
// hs[M,128](fp16) = (A[M,256](fp32) @ W1T^T) * dis[row].  BM=64, BN=128, BK=64.
// 4 waves in 2x2: each 32x64.  Grid depth ~6 blocks/CU.
__global__ __launch_bounds__(256) void gemm1_mfma(const float* __restrict__ A,
                                                  const half_t* __restrict__ BT,
                                                  const float* __restrict__ dis,
                                                  half_t* __restrict__ C, int M) {
    __shared__ half_t As[64][72];
    __shared__ half_t Bs[128][72];
    const int tid = threadIdx.x;
    const int block_row = blockIdx.x * 64;
    const int wave = tid >> 6, lane = tid & 63;
    const int wm = (wave & 1) * 32, wn = (wave >> 1) * 64;
    const int l16 = lane & 15, quad = lane >> 4;

    f32x4 acc[2][4] = {};
    float4 pa[4];
    f16x8  pb[4];

    // prefetch k0 = 0
    #pragma unroll
    for (int i = 0; i < 4; i++) {
        int idx = tid + i * 256;
        int r = idx >> 4, c = idx & 15;
        int row = block_row + r; row = row < M ? row : M - 1;
        pa[i] = ((const float4*)(A + (size_t)row * 256))[c];
    }
    #pragma unroll
    for (int i = 0; i < 4; i++) {
        int idx = tid + i * 256;
        int nr = idx >> 3, kc = idx & 7;
        pb[i] = *(const f16x8*)(BT + (size_t)nr * 256 + kc * 8);
    }

    for (int k0 = 0; k0 < 256; k0 += 64) {
        // drain prefetch into LDS
        #pragma unroll
        for (int i = 0; i < 4; i++) {
            int idx = tid + i * 256;
            int r = idx >> 4, c = idx & 15;
            f16x4 hv = { (half_t)pa[i].x, (half_t)pa[i].y, (half_t)pa[i].z, (half_t)pa[i].w };
            *(f16x4*)(&As[r][c * 4]) = hv;
        }
        #pragma unroll
        for (int i = 0; i < 4; i++) {
            int idx = tid + i * 256;
            int nr = idx >> 3, kc = idx & 7;
            *(f16x8*)(&Bs[nr][kc * 8]) = pb[i];
        }
        __syncthreads();

        // issue next tile's global loads (overlap with MFMA below)
        if (k0 < 192) {
            #pragma unroll
            for (int i = 0; i < 4; i++) {
                int idx = tid + i * 256;
                int r = idx >> 4, c = idx & 15;
                int row = block_row + r; row = row < M ? row : M - 1;
                pa[i] = ((const float4*)(A + (size_t)row * 256 + k0 + 64))[c];
            }
            #pragma unroll
            for (int i = 0; i < 4; i++) {
                int idx = tid + i * 256;
                int nr = idx >> 3, kc = idx & 7;
                pb[i] = *(const f16x8*)(BT + (size_t)nr * 256 + k0 + 64 + kc * 8);
            }
        }

        #pragma unroll
        for (int ks = 0; ks < 2; ks++) {
            f16x8 af[2], bf[4];
            #pragma unroll
            for (int mt = 0; mt < 2; mt++)
                af[mt] = *(const f16x8*)(&As[wm + mt * 16 + l16][ks * 32 + quad * 8]);
            #pragma unroll
            for (int nt = 0; nt < 4; nt++)
                bf[nt] = *(const f16x8*)(&Bs[wn + nt * 16 + l16][ks * 32 + quad * 8]);
            #pragma unroll
            for (int mt = 0; mt < 2; mt++)
                #pragma unroll
                for (int nt = 0; nt < 4; nt++)
                    acc[mt][nt] = __builtin_amdgcn_mfma_f32_16x16x32_f16(af[mt], bf[nt], acc[mt][nt], 0, 0, 0);
        }
        __syncthreads();
    }

    #pragma unroll
    for (int mt = 0; mt < 2; mt++) {
        #pragma unroll
        for (int r = 0; r < 4; r++) {
            int row = block_row + wm + mt * 16 + quad * 4 + r;
            if (row < M) {
                float d = dis[row];
                #pragma unroll
                for (int nt = 0; nt < 4; nt++) {
                    int col = wn + nt * 16 + l16;
                    C[(size_t)row * 128 + col] = (half_t)(acc[mt][nt][r] * d);
                }
            }
        }
    }
}

// ==================== MFMA GEMM2 (pipelined) ====================
// [mu|sig][M,64](fp32) = A[M,128](fp16) @ WcatT^T + bias.  BM=64, BN=128.
__global__ __launch_bounds__(256) void gemm2_mfma(const half_t* __restrict__ A,
                                                  const half_t* __restrict__ BT,
                                                  const float* __restrict__ bmu,
                                                  const float* __restrict__ bvar,
                                                  float* __restrict__ out_mu,
                                                  float* __restrict__ out_sig, int M) {
    __shared__ half_t As[64][72];
    __shared__ half_t Bs[128][72];
    const int tid = threadIdx.x;
    const int block_row = blockIdx.x * 64;
    const int wave = tid >> 6, lane = tid & 63;
    const int wm = (wave & 1) * 32, wn = (wave >> 1) * 64;
    const int l16 = lane & 15, quad = lane >> 4;

    f32x4 acc[2][4] = {};
    f16x8 pa[2], pb[4];

    #pragma unroll
    for (int i = 0; i < 2; i++) {
        int idx = tid + i * 256;
        int r = idx >> 3, kc = idx & 7;
        int row = block_row + r; row = row < M ? row : M - 1;
        pa[i] = *(const f16x8*)(A + (size_t)row * 128 + kc * 8);
    }
    #pragma unroll
    for (int i = 0; i < 4; i++) {
        int idx = tid + i * 256;
        int nr = idx >> 3, kc = idx & 7;
        pb[i] = *(const f16x8*)(BT + (size_t)nr * 128 + kc * 8);
    }

    for (int k0 = 0; k0 < 128; k0 += 64) {
        #pragma unroll
        for (int i = 0; i < 2; i++) {
            int idx = tid + i * 256;
            int r = idx >> 3, kc = idx & 7;
            *(f16x8*)(&As[r][kc * 8]) = pa[i];
        }
        #pragma unroll
        for (int i = 0; i < 4; i++) {
            int idx = tid + i * 256;
            int nr = idx >> 3, kc = idx & 7;
            *(f16x8*)(&Bs[nr][kc * 8]) = pb[i];
        }
        __syncthreads();

        if (k0 < 64) {
            #pragma unroll
            for (int i = 0; i < 2; i++) {
                int idx = tid + i * 256;
                int r = idx >> 3, kc = idx & 7;
                int row = block_row + r; row = row < M ? row : M - 1;
                pa[i] = *(const f16x8*)(A + (size_t)row * 128 + 64 + kc * 8);
            }
            #pragma unroll
            for (int i = 0; i < 4; i++) {
                int idx = tid + i * 256;
                int nr = idx >> 3, kc = idx & 7;
                pb[i] = *(const f16x8*)(BT + (size_t)nr * 128 + 64 + kc * 8);
            }
        }

        #pragma unroll
        for (int ks = 0; ks < 2; ks++) {
            f16x8 af[2], bf[4];
            #pragma unroll
            for (int mt = 0; mt < 2; mt++)
                af[mt] = *(const f16x8*)(&As[wm + mt * 16 + l16][ks * 32 + quad * 8]);
            #pragma unroll
            for (int nt = 0; nt < 4; nt++)
                bf[nt] = *(const f16x8*)(&Bs[wn + nt * 16 + l16][ks * 32 + quad * 8]);
            #pragma unroll
            for (int mt = 0; mt < 2; mt++)
                #pragma unroll
                for (int nt = 0; nt < 4; nt++)
                    acc[mt][nt] = __builtin_amdgcn_mfma_f32_16x16x32_f16(af[mt], bf[nt], acc[mt][nt], 0, 0, 0);
        }
        __syncthreads();
    }

    float bias[4];
    int cols[4];
    #pragma unroll
    for (int nt = 0; nt < 4; nt++) {
        int col = wn + nt * 16 + l16;
        cols[nt] = col;
        bias[nt] = (col < DOUT) ? bmu[col] : bvar[col - DOUT];
    }

    #pragma unroll
    for (int mt = 0; mt < 2; mt++) {
        #pragma unroll
        for (int r = 0; r < 4; r++) {
            int row = block_row + wm + mt * 16 + quad * 4 + r;
            if (row < M) {
                #pragma unroll
                for (int nt = 0; nt < 4; nt++) {
                    int col = cols[nt];
                    float v = acc[mt][nt][r] + bias[nt];
                    if (col < DOUT) out_mu[(size_t)row * DOUT + col] = v;
                    else            out_sig[(size_t)row * DOUT + (col - DOUT)] = v;
                }
            }
        }
    }
}

// ==================== aggregation on pre-scaled features ====================
// acc_i = hin[i] + sum_{s in N(i)} hin[s]          (one gather per edge)
// LAYER1: hout = relu(di*acc + b1)*di   LAYER2: hout = di*acc
template <bool LAYER1>
__global__ __launch_bounds__(256) void agg_kernel(const int* __restrict__ rowptr_end,
                                                  const int* __restrict__ col,
                                                  const float* __restrict__ dis,
                                                  const half_t* __restrict__ hin,
                                                  half_t* __restrict__ hout,
                                                  const float* __restrict__ bias, int n) {
    int node = blockIdx.x * 8 + (threadIdx.x >> 5);
    if (node >= n) return;
    int lane = threadIdx.x & 31;
    int beg = (node == 0) ? 0 : rowptr_end[node - 1];
    int end = rowptr_end[node];
    const f16x4* hv = (const f16x4*)hin;

    f16x4 sv = hv[(size_t)node * 32 + lane];
    float ax = (float)sv[0], ay = (float)sv[1], az = (float)sv[2], aw = (float)sv[3];

    int e = beg;
    for (; e + 3 < end; e += 4) {
        int s0 = col[e], s1 = col[e + 1], s2 = col[e + 2], s3 = col[e + 3];
        f16x4 v0 = hv[(size_t)s0 * 32 + lane];
        f16x4 v1 = hv[(size_t)s1 * 32 + lane];
        f16x4 v2 = hv[(size_t)s2 * 32 + lane];
        f16x4 v3 = hv[(size_t)s3 * 32 + lane];
        ax += (float)v0[0] + (float)v1[0] + (float)v2[0] + (float)v3[0];
        ay += (float)v0[1] + (float)v1[1] + (float)v2[1] + (float)v3[1];
        az += (float)v0[2] + (float)v1[2] + (float)v2[2] + (float)v3[2];
        aw += (float)v0[3] + (float)v1[3] + (float)v2[3] + (float)v3[3];
    }
    for (; e < end; e++) {
        int s0 = col[e];
        f16x4 v0 = hv[(size_t)s0 * 32 + lane];
        ax += (float)v0[0]; ay += (float)v0[1]; az += (float)v0[2]; aw += (float)v0[3];
    }

    float di = dis[node];
    if (LAYER1) {
        const float4 b = ((const float4*)bias)[lane];
        ax = ax * di + b.x; ay = ay * di + b.y; az = az * di + b.z; aw = aw * di + b.w;
        ax = (ax > 0.f ? ax : 0.f) * di;
        ay = (ay > 0.f ? ay : 0.f) * di;
        az = (az > 0.f ? az : 0.f) * di;
        aw = (aw > 0.f ? aw : 0.f) * di;
    } else {
        ax *= di; ay *= di; az *= di; aw *= di;
    }
    f16x4 o = { (half_t)ax, (half_t)ay, (half_t)az, (half_t)aw };
    ((f16x4*)hout)[(size_t)node * 32 + lane] = o;
}

extern "C" void kernel_launch(void* const* d_in, const int* in_sizes, int n_in,
                              void* d_out, int out_size, void* d_ws, size_t ws_size,
                              hipStream_t stream) {
    const float* x    = (const float*)d_in[0];
    const int*   ei   = (const int*)d_in[1];
    const float* W1   = (const float*)d_in[2];
    const float* b1   = (const float*)d_in[3];
    const float* Wmu  = (const float*)d_in[4];
    const float* bmu  = (const float*)d_in[5];
    const float* Wvar = (const float*)d_in[6];
    const float* bvar = (const float*)d_in[7];

    const int n = in_sizes[0] / 256;     // 100000
    const int E = in_sizes[1] / 2;       // 1600000
    const int* src = ei;
    const int* dst = ei + E;

    const int NB      = (n + 255) >> NB_SHIFT;
    const int nblocks = (E + CHUNK - 1) / CHUNK;
    const int flat    = NB * nblocks;
    const int nb_scan = (flat + 1023) / 1024;

    char* ws = (char*)d_ws;
    size_t off = 0;
    auto alloc = [&](size_t bytes) { void* p = ws + off; off = (off + bytes + 255) & ~(size_t)255; return p; };
    float*  dis     = (float*) alloc((size_t)n * 4);
    int*    rowptr  = (int*)   alloc((size_t)n * 4);
    int*    counts  = (int*)   alloc((size_t)flat * 4);
    int*    offsets = (int*)   alloc((size_t)flat * 4);
    int*    bsum    = (int*)   alloc((size_t)nb_scan * 4 + 256);
    int2*   binned  = (int2*)  alloc((size_t)E * 8);
    int*    col     = (int*)   alloc((size_t)E * 4);
    half_t* W1T     = (half_t*)alloc((size_t)256 * HID * 2);
    half_t* WcatT   = (half_t*)alloc((size_t)HID * HID * 2);
    half_t* hs      = (half_t*)alloc((size_t)n * HID * 2);  // gemm1 out (pre-scaled); reused as agg2
    half_t* h1s     = (half_t*)alloc((size_t)n * HID * 2);  // relu out (pre-scaled)
    half_t* agg2    = hs;                                   // alias: hs dead after agg1

    float* out_mu  = (float*)d_out;
    float* out_sig = (float*)d_out + (size_t)n * DOUT;

    // CSR build
    bincount_kernel<<<nblocks, 256, 0, stream>>>(dst, counts, E, nblocks, NB);
    scan1_kernel<<<nb_scan, 256, 0, stream>>>(counts, offsets, bsum, flat);
    scan2_kernel<<<1, 64, 0, stream>>>(bsum, nb_scan);
    scan3_kernel<<<(flat + 255) / 256, 256, 0, stream>>>(offsets, bsum, flat);
    binscatter_kernel<<<nblocks, 256, 0, stream>>>(src, dst, offsets, binned, E, nblocks, NB);
    csrbuild_kernel<<<NB, 256, 0, stream>>>(binned, offsets, rowptr, col, dis, E, nblocks, NB, n);

    // weights
    w1t_kernel<<<(256 * HID) / 256, 256, 0, stream>>>(W1, W1T);
    wcatt_kernel<<<(HID * HID) / 256, 256, 0, stream>>>(Wmu, Wvar, WcatT);

    // dense + sparse pipeline
    gemm1_mfma<<<(n + 63) / 64, 256, 0, stream>>>(x, W1T, dis, hs, n);
    agg_kernel<true><<<(n + 7) / 8, 256, 0, stream>>>(rowptr, col, dis, hs, h1s, b1, n);
    agg_kernel<false><<<(n + 7) / 8, 256, 0, stream>>>(rowptr, col, dis, h1s, agg2, nullptr, n);
    gemm2_mfma<<<(n + 63) / 64, 256, 0, stream>>>(agg2, WcatT, bmu, bvar, out_mu, out_sig, n);
}